// Round 1
// baseline (270.206 us; speedup 1.0000x reference)
//
#include <hip/hip_runtime.h>

typedef _Float16 f16;
typedef _Float16 f16x8 __attribute__((ext_vector_type(8)));
typedef float f32x4 __attribute__((ext_vector_type(4)));

#define XN_STRIDE 264   // f16 units; 528B row stride: 16B-aligned, 132-word => 2-way bank alias (free)
#define QS 40           // 80B stride
#define VS 72           // 144B stride
#define PS 72

__device__ __forceinline__ f32x4 mfma16(f16x8 a, f16x8 b, f32x4 c){
  return __builtin_amdgcn_mfma_f32_16x16x32_f16(a, b, c, 0, 0, 0);
}

// ---------------- kernel 0: weights fp32 -> fp16 ----------------
__global__ __launch_bounds__(256) void k_cvt(const float* __restrict__ wqkv,
                                             const float* __restrict__ wproj,
                                             f16* __restrict__ wqkv_h,
                                             f16* __restrict__ wproj_h){
  int i = blockIdx.x*256 + threadIdx.x;
  for (int idx = i; idx < 768*256; idx += gridDim.x*256) wqkv_h[idx] = (f16)wqkv[idx];
  for (int idx = i; idx < 256*256; idx += gridDim.x*256) wproj_h[idx] = (f16)wproj[idx];
}

// ---------------- kernel 1: LayerNorm + QKV GEMM (per (b,h) row of 64 positions) ----------------
// q_ws/k_ws: [row][w][c] f16 (c = head*32+d).  vt_ws: [row][c][w] f16 (V pre-transposed).
__global__ __launch_bounds__(256) void k_lnqkv(const float* __restrict__ x,
    const float* __restrict__ gamma, const float* __restrict__ beta,
    const f16* __restrict__ wqkv,
    f16* __restrict__ qws, f16* __restrict__ kws, f16* __restrict__ vtws)
{
  __shared__ f16 xn[64*XN_STRIDE];
  __shared__ float red[2][4][64];
  __shared__ float mrs[2][64];
  __shared__ float gb[2][256];
  const int t = threadIdx.x;
  const int lane = t & 63;
  const int wv = t >> 6;
  const int row = blockIdx.x;           // 0..1023
  const int b = row >> 6, hh = row & 63;
  const float* xrow = x + (size_t)b*256*4096 + hh*64;   // + c*4096 + w

  gb[0][t] = gamma[t]; gb[1][t] = beta[t];

  // ---- stats: thread (w=lane, channel-group wv) ----
  const int w = lane;
  float s = 0.f, s2 = 0.f;
  for (int i = 0; i < 64; ++i){
    float v = xrow[(size_t)(wv*64 + i)*4096 + w];
    s += v; s2 += v*v;
  }
  red[0][wv][w] = s; red[1][wv][w] = s2;
  __syncthreads();
  if (t < 64){
    float ss = red[0][0][t]+red[0][1][t]+red[0][2][t]+red[0][3][t];
    float qq = red[1][0][t]+red[1][1][t]+red[1][2][t]+red[1][3][t];
    float mu = ss*(1.f/256.f);
    float var = qq*(1.f/256.f) - mu*mu;
    mrs[0][t] = mu; mrs[1][t] = rsqrtf(var + 1e-5f);
  }
  __syncthreads();
  {
    float mu = mrs[0][w], rs = mrs[1][w];
    for (int i = 0; i < 64; ++i){
      int c = wv*64 + i;
      float v = xrow[(size_t)c*4096 + w];
      xn[w*XN_STRIDE + c] = (f16)((v - mu)*rs*gb[0][c] + gb[1][c]);
    }
  }
  __syncthreads();

  const int l15 = lane & 15, l16 = lane >> 4;

  // ---- Q and K chunks: wave wv computes output cols [wv*64, wv*64+64) ----
  for (int qk = 0; qk < 2; ++qk){
    f16* outp = qk ? kws : qws;
    const int wbase = qk*256 + wv*64;   // rows of wqkv
    f32x4 acc[4][4] = {};
    for (int kk = 0; kk < 8; ++kk){
      const int k0 = kk*32 + l16*8;
      f16x8 a[4], bb[4];
      for (int m = 0; m < 4; ++m) a[m]  = *(const f16x8*)&xn[(m*16 + l15)*XN_STRIDE + k0];
      for (int n = 0; n < 4; ++n) bb[n] = *(const f16x8*)&wqkv[(size_t)(wbase + n*16 + l15)*256 + k0];
      for (int m = 0; m < 4; ++m)
        for (int n = 0; n < 4; ++n)
          acc[m][n] = mfma16(a[m], bb[n], acc[m][n]);
    }
    f16* orow = outp + (size_t)row*64*256;
    for (int m = 0; m < 4; ++m)
      for (int n = 0; n < 4; ++n)
        for (int r = 0; r < 4; ++r){
          int wp = m*16 + l16*4 + r;            // position
          int c  = wv*64 + n*16 + l15;          // channel
          orow[wp*256 + c] = (f16)acc[m][n][r];
        }
  }

  // ---- V with swapped operands: A = W_v rows (M=channel), B^T = xn (N=position) ----
  {
    f32x4 acc[4][4] = {};
    for (int kk = 0; kk < 8; ++kk){
      const int k0 = kk*32 + l16*8;
      f16x8 a[4], bb[4];
      for (int m = 0; m < 4; ++m) a[m]  = *(const f16x8*)&wqkv[(size_t)(512 + wv*64 + m*16 + l15)*256 + k0];
      for (int n = 0; n < 4; ++n) bb[n] = *(const f16x8*)&xn[(n*16 + l15)*XN_STRIDE + k0];
      for (int m = 0; m < 4; ++m)
        for (int n = 0; n < 4; ++n)
          acc[m][n] = mfma16(a[m], bb[n], acc[m][n]);
    }
    f16* vrow = vtws + (size_t)row*256*64;
    for (int m = 0; m < 4; ++m)
      for (int n = 0; n < 4; ++n)
        for (int r = 0; r < 4; ++r){
          int cv = wv*64 + m*16 + l16*4 + r;    // v-channel (row of vT)
          int wp = n*16 + l15;                  // position
          vrow[cv*64 + wp] = (f16)acc[m][n][r];
        }
  }
}

// ---------------- kernel 2: attention per (row, head), 1 wave ----------------
__global__ __launch_bounds__(64) void k_attn(const f16* __restrict__ qws, const f16* __restrict__ kws,
                                             const f16* __restrict__ vtws, f16* __restrict__ aws)
{
  __shared__ f16 ql[64*QS], kl[64*QS], vtl[32*VS], pl[64*PS];
  const int lane = threadIdx.x;
  const int row  = blockIdx.x >> 3;
  const int head = blockIdx.x & 7;
  const f16* qp = qws + (size_t)row*64*256 + head*32;
  const f16* kp = kws + (size_t)row*64*256 + head*32;
  const f16* vp = vtws + ((size_t)row*256 + head*32)*64;

  for (int j = 0; j < 32; j += 8){
    *(f16x8*)&ql[lane*QS + j] = *(const f16x8*)&qp[lane*256 + j];
    *(f16x8*)&kl[lane*QS + j] = *(const f16x8*)&kp[lane*256 + j];
  }
  for (int c2 = 0; c2 < 4; ++c2){
    int chunk = lane + c2*64;
    int d = chunk >> 3, j8 = chunk & 7;
    *(f16x8*)&vtl[d*VS + j8*8] = *(const f16x8*)&vp[d*64 + j8*8];
  }
  __syncthreads();

  const int l15 = lane & 15, l16 = lane >> 4;

  // S = Q K^T  (M=64 q, N=64 kpos, K=32)
  f32x4 sa[4][4];
  {
    const int k0 = l16*8;
    f16x8 a[4], bb[4];
    for (int m = 0; m < 4; ++m) a[m]  = *(const f16x8*)&ql[(m*16 + l15)*QS + k0];
    for (int n = 0; n < 4; ++n) bb[n] = *(const f16x8*)&kl[(n*16 + l15)*QS + k0];
    f32x4 z = {0.f, 0.f, 0.f, 0.f};
    for (int m = 0; m < 4; ++m)
      for (int n = 0; n < 4; ++n)
        sa[m][n] = mfma16(a[m], bb[n], z);
  }

  // softmax over kpos: per lane 16 rows x 4 cols; row-reduce across 16-lane group
  const float sc = 0.17677669529663687f;   // 32^-0.5
  for (int m = 0; m < 4; ++m)
    for (int r = 0; r < 4; ++r){
      float mx = fmaxf(fmaxf(sa[m][0][r], sa[m][1][r]), fmaxf(sa[m][2][r], sa[m][3][r]));
      mx = fmaxf(mx, __shfl_xor(mx, 1));
      mx = fmaxf(mx, __shfl_xor(mx, 2));
      mx = fmaxf(mx, __shfl_xor(mx, 4));
      mx = fmaxf(mx, __shfl_xor(mx, 8));
      float pv[4]; float sum = 0.f;
      for (int n = 0; n < 4; ++n){ float p = __expf((sa[m][n][r] - mx)*sc); pv[n] = p; sum += p; }
      sum += __shfl_xor(sum, 1);
      sum += __shfl_xor(sum, 2);
      sum += __shfl_xor(sum, 4);
      sum += __shfl_xor(sum, 8);
      float inv = 1.f/sum;
      int q = m*16 + l16*4 + r;
      for (int n = 0; n < 4; ++n) pl[q*PS + n*16 + l15] = (f16)(pv[n]*inv);
    }
  __syncthreads();

  // O = P V  (A = P[q][k], B^T = vT[d][k])
  f32x4 oa[4][2] = {};
  for (int kk = 0; kk < 2; ++kk){
    const int k0 = kk*32 + l16*8;
    f16x8 a[4], bb[2];
    for (int m = 0; m < 4; ++m) a[m]  = *(const f16x8*)&pl[(m*16 + l15)*PS + k0];
    for (int n = 0; n < 2; ++n) bb[n] = *(const f16x8*)&vtl[(n*16 + l15)*VS + k0];
    for (int m = 0; m < 4; ++m)
      for (int n = 0; n < 2; ++n)
        oa[m][n] = mfma16(a[m], bb[n], oa[m][n]);
  }
  f16* ap = aws + (size_t)row*64*256 + head*32;
  for (int m = 0; m < 4; ++m)
    for (int n = 0; n < 2; ++n)
      for (int r = 0; r < 4; ++r){
        int wp = m*16 + l16*4 + r;
        ap[wp*256 + n*16 + l15] = (f16)oa[m][n][r];
      }
}

// ---------------- kernel 3: out-proj GEMM + bias + NCHW transpose ----------------
__global__ __launch_bounds__(256) void k_proj(const f16* __restrict__ aws, const f16* __restrict__ wproj,
                                              const float* __restrict__ bproj, float* __restrict__ out)
{
  __shared__ __align__(16) char smem[64*XN_STRIDE*2];   // 33792 B, reused
  f16* al = (f16*)smem;
  float* ol = (float*)smem;
  const int t = threadIdx.x;
  const int lane = t & 63;
  const int wv = t >> 6;
  const int row = blockIdx.x;
  const int b = row >> 6, hh = row & 63;
  const f16* ap = aws + (size_t)row*64*256;

  for (int it = 0; it < 8; ++it){
    int chunk = t + it*256;
    int r = chunk >> 5, j8 = chunk & 31;
    *(f16x8*)&al[r*XN_STRIDE + j8*8] = *(const f16x8*)&ap[r*256 + j8*8];
  }
  __syncthreads();

  const int l15 = lane & 15, l16 = lane >> 4;
  f32x4 acc[4][4] = {};
  for (int kk = 0; kk < 8; ++kk){
    const int k0 = kk*32 + l16*8;
    f16x8 a[4], bb[4];
    for (int m = 0; m < 4; ++m) a[m]  = *(const f16x8*)&al[(m*16 + l15)*XN_STRIDE + k0];
    for (int n = 0; n < 4; ++n) bb[n] = *(const f16x8*)&wproj[(size_t)(wv*64 + n*16 + l15)*256 + k0];
    for (int m = 0; m < 4; ++m)
      for (int n = 0; n < 4; ++n)
        acc[m][n] = mfma16(a[m], bb[n], acc[m][n]);
  }
  float bia[4];
  for (int n = 0; n < 4; ++n) bia[n] = bproj[wv*64 + n*16 + l15];
  __syncthreads();   // done with al; reuse as ol

  float* olw = ol + wv*(32*65);
  for (int half = 0; half < 2; ++half){
    __syncthreads();
    for (int n2 = 0; n2 < 2; ++n2){
      int n = half*2 + n2;
      for (int m = 0; m < 4; ++m)
        for (int r = 0; r < 4; ++r)
          olw[(n2*16 + l15)*65 + m*16 + l16*4 + r] = acc[m][n][r] + bia[n];
    }
    __syncthreads();
    for (int rr = 0; rr < 32; ++rr){
      int dout = wv*64 + half*32 + rr;
      out[(size_t)(b*256 + dout)*4096 + hh*64 + lane] = olw[rr*65 + lane];
    }
  }
}

extern "C" void kernel_launch(void* const* d_in, const int* in_sizes, int n_in,
                              void* d_out, int out_size, void* d_ws, size_t ws_size,
                              hipStream_t stream)
{
  const float* x     = (const float*)d_in[0];
  const float* wqkv  = (const float*)d_in[1];
  const float* wproj = (const float*)d_in[2];
  const float* bproj = (const float*)d_in[3];
  const float* gamma = (const float*)d_in[4];
  const float* beta  = (const float*)d_in[5];
  float* out = (float*)d_out;

  f16* ws = (f16*)d_ws;
  f16* wqkv_h  = ws;                       // 196608
  f16* wproj_h = ws + 196608;              // 65536
  f16* qws  = ws + 262144;                 // 1024*64*256
  f16* kws  = qws + 16777216;
  f16* vtws = kws + 16777216;
  f16* aws  = vtws + 16777216;

  k_cvt  <<<256, 256, 0, stream>>>(wqkv, wproj, wqkv_h, wproj_h);
  k_lnqkv<<<1024, 256, 0, stream>>>(x, gamma, beta, wqkv_h, qws, kws, vtws);
  k_attn <<<8192, 64, 0, stream>>>(qws, kws, vtws, aws);
  k_proj <<<1024, 256, 0, stream>>>(aws, wproj_h, bproj, out);
}

// Round 4
// 216.921 us; speedup vs baseline: 1.2456x; 1.2456x over previous
//
#include <hip/hip_runtime.h>

typedef _Float16 f16;
typedef _Float16 f16x8 __attribute__((ext_vector_type(8)));
typedef float f32x4 __attribute__((ext_vector_type(4)));

#define XNS 264   // xn/al row stride in f16 (528B = 33*16B, balanced for b128 frag reads)
#define QKS 40    // q/k row stride (80B)
#define VTS 72    // vt row stride (144B)
#define PSS 72    // p row stride

__device__ __forceinline__ f32x4 mfma16(f16x8 a, f16x8 b, f32x4 c){
  return __builtin_amdgcn_mfma_f32_16x16x32_f16(a, b, c, 0, 0, 0);
}

// ---------------- kernel 0: weights fp32 -> fp16 ----------------
__global__ __launch_bounds__(256) void k_cvt(const float* __restrict__ wqkv,
                                             const float* __restrict__ wproj,
                                             f16* __restrict__ wqkv_h,
                                             f16* __restrict__ wproj_h){
  int i = blockIdx.x*256 + threadIdx.x;
  for (int idx = i; idx < 768*256; idx += gridDim.x*256) wqkv_h[idx] = (f16)wqkv[idx];
  for (int idx = i; idx < 256*256; idx += gridDim.x*256) wproj_h[idx] = (f16)wproj[idx];
}

// ---------------- fused: LN + QKV + attention + proj + NCHW store ----------------
// One block per (b, h-row): 512 threads = 8 waves; wave h owns head h (channels h*32..h*32+31).
// LDS: xn[64][264] f16 (reused as attn-out al) | per-wave {qs,ks,vts} (ps, ol overlay qs+ks)
__global__ __launch_bounds__(512) void k_fused(const float* __restrict__ x,
    const float* __restrict__ gamma, const float* __restrict__ beta,
    const f16* __restrict__ wqkv, const f16* __restrict__ wproj,
    const float* __restrict__ bproj, float* __restrict__ out)
{
  __shared__ f16 xn[64*XNS];            // 33792 B; reused as al in phases 3-4
  __shared__ f16 perw[8][7424];         // 14848 B/wave: qs[0..2559] ks[2560..5119] vts[5120..7423]
  __shared__ float red[2][8][64];       // 4096 B
  __shared__ float mrs[2][64];          // 512 B  -> total 157184 B

  const int t = threadIdx.x;
  const int lane = t & 63;
  const int h = t >> 6;                 // wave id == head id
  const int l15 = lane & 15, l16 = lane >> 4;
  const int row = blockIdx.x;           // 0..1023
  const int b = row >> 6, hh = row & 63;
  const float* xrow = x + (size_t)b*256*4096 + hh*64;   // + c*4096 + w

  // ---- phase 1: LN stats (wave h covers channels h*32..+31; lane = w) ----
  {
    float s = 0.f, s2 = 0.f;
    for (int i = 0; i < 32; ++i){
      float v = xrow[(size_t)(h*32 + i)*4096 + lane];
      s += v; s2 += v*v;
    }
    red[0][h][lane] = s; red[1][h][lane] = s2;
  }
  __syncthreads();
  if (t < 64){
    float ss = 0.f, qq = 0.f;
    for (int j = 0; j < 8; ++j){ ss += red[0][j][t]; qq += red[1][j][t]; }
    float mu = ss*(1.f/256.f);
    float var = qq*(1.f/256.f) - mu*mu;
    mrs[0][t] = mu; mrs[1][t] = rsqrtf(var + 1e-5f);
  }
  __syncthreads();

  // ---- phase 1b: normalize + transpose into xn[w][c] ----
  {
    float mu = mrs[0][lane], rs = mrs[1][lane];
    for (int i = 0; i < 32; ++i){
      int c = h*32 + i;
      float v = xrow[(size_t)c*4096 + lane];
      xn[lane*XNS + c] = (f16)((v - mu)*rs*gamma[c] + beta[c]);
    }
  }
  __syncthreads();

  f16* qs  = &perw[h][0];
  f16* ks  = &perw[h][2560];
  f16* vts = &perw[h][5120];

  // ---- phase 2: Q, K (M=64 pos, N=32 ch) ----
  for (int qk = 0; qk < 2; ++qk){
    const f16* wb = wqkv + (size_t)(qk*256 + h*32)*256;
    f32x4 acc[4][2] = {};
    for (int kk = 0; kk < 8; ++kk){
      int k0 = kk*32 + l16*8;
      f16x8 a[4], bb[2];
      for (int m = 0; m < 4; ++m) a[m]  = *(const f16x8*)&xn[(m*16 + l15)*XNS + k0];
      for (int n = 0; n < 2; ++n) bb[n] = *(const f16x8*)&wb[(size_t)(n*16 + l15)*256 + k0];
      for (int m = 0; m < 4; ++m)
        for (int n = 0; n < 2; ++n)
          acc[m][n] = mfma16(a[m], bb[n], acc[m][n]);
    }
    f16* dst = qk ? ks : qs;
    for (int m = 0; m < 4; ++m)
      for (int n = 0; n < 2; ++n)
        for (int r = 0; r < 4; ++r){
          int pos = m*16 + l16*4 + r;
          int d   = n*16 + l15;
          dst[pos*QKS + d] = (f16)acc[m][n][r];
        }
  }
  // ---- phase 2v: V swapped (A = Wv rows -> M=ch, B = xn -> N=pos) => vt[d][pos] ----
  {
    const f16* wv = wqkv + (size_t)(512 + h*32)*256;
    f32x4 acc[2][4] = {};
    for (int kk = 0; kk < 8; ++kk){
      int k0 = kk*32 + l16*8;
      f16x8 a[2], bb[4];
      for (int m = 0; m < 2; ++m) a[m]  = *(const f16x8*)&wv[(size_t)(m*16 + l15)*256 + k0];
      for (int n = 0; n < 4; ++n) bb[n] = *(const f16x8*)&xn[(n*16 + l15)*XNS + k0];
      for (int m = 0; m < 2; ++m)
        for (int n = 0; n < 4; ++n)
          acc[m][n] = mfma16(a[m], bb[n], acc[m][n]);
    }
    for (int m = 0; m < 2; ++m)
      for (int n = 0; n < 4; ++n)
        for (int r = 0; r < 4; ++r){
          int d   = m*16 + l16*4 + r;
          int pos = n*16 + l15;
          vts[d*VTS + pos] = (f16)acc[m][n][r];
        }
  }
  __syncthreads();   // xn reads done (al overlay safe); qs/ks/vts visible cross-lane

  // ---- phase 3: attention for head h ----
  f32x4 sa[4][4];
  {
    int k0 = l16*8;
    f16x8 a[4], bb[4];
    for (int m = 0; m < 4; ++m) a[m]  = *(const f16x8*)&qs[(m*16 + l15)*QKS + k0];
    for (int n = 0; n < 4; ++n) bb[n] = *(const f16x8*)&ks[(n*16 + l15)*QKS + k0];
    f32x4 z = {0.f,0.f,0.f,0.f};
    for (int m = 0; m < 4; ++m)
      for (int n = 0; n < 4; ++n)
        sa[m][n] = mfma16(a[m], bb[n], z);
  }
  f16* ps = &perw[h][0];   // overlays qs+ks (own wave only)
  {
    const float sc = 0.17677669529663687f;   // 32^-0.5
    for (int m = 0; m < 4; ++m)
      for (int r = 0; r < 4; ++r){
        float mx = fmaxf(fmaxf(sa[m][0][r], sa[m][1][r]), fmaxf(sa[m][2][r], sa[m][3][r]));
        mx = fmaxf(mx, __shfl_xor(mx, 1));
        mx = fmaxf(mx, __shfl_xor(mx, 2));
        mx = fmaxf(mx, __shfl_xor(mx, 4));
        mx = fmaxf(mx, __shfl_xor(mx, 8));
        float pv[4]; float sum = 0.f;
        for (int n = 0; n < 4; ++n){ float p = __expf((sa[m][n][r] - mx)*sc); pv[n] = p; sum += p; }
        sum += __shfl_xor(sum, 1);
        sum += __shfl_xor(sum, 2);
        sum += __shfl_xor(sum, 4);
        sum += __shfl_xor(sum, 8);
        float inv = 1.f/sum;
        int q = m*16 + l16*4 + r;
        for (int n = 0; n < 4; ++n) ps[q*PSS + n*16 + l15] = (f16)(pv[n]*inv);
      }
  }
  __syncthreads();   // ps visible cross-lane

  f16* al = xn;      // attn output tile, overlays xn
  {
    f32x4 oa[4][2] = {};
    for (int kk = 0; kk < 2; ++kk){
      int k0 = kk*32 + l16*8;
      f16x8 a[4], bb[2];
      for (int m = 0; m < 4; ++m) a[m]  = *(const f16x8*)&ps[(m*16 + l15)*PSS + k0];
      for (int n = 0; n < 2; ++n) bb[n] = *(const f16x8*)&vts[(n*16 + l15)*VTS + k0];
      for (int m = 0; m < 4; ++m)
        for (int n = 0; n < 2; ++n)
          oa[m][n] = mfma16(a[m], bb[n], oa[m][n]);
    }
    for (int m = 0; m < 4; ++m)
      for (int n = 0; n < 2; ++n)
        for (int r = 0; r < 4; ++r){
          int pos = m*16 + l16*4 + r;
          al[pos*XNS + h*32 + n*16 + l15] = (f16)oa[m][n][r];
        }
  }
  __syncthreads();   // al complete from all waves

  // ---- phase 4: out-proj (wave h -> output channels h*32..+31) + NCHW store ----
  {
    f32x4 acc[4][2] = {};
    for (int kk = 0; kk < 8; ++kk){
      int k0 = kk*32 + l16*8;
      f16x8 a[4], bb[2];
      for (int m = 0; m < 4; ++m) a[m]  = *(const f16x8*)&al[(m*16 + l15)*XNS + k0];
      for (int n = 0; n < 2; ++n) bb[n] = *(const f16x8*)&wproj[(size_t)(h*32 + n*16 + l15)*256 + k0];
      for (int m = 0; m < 4; ++m)
        for (int n = 0; n < 2; ++n)
          acc[m][n] = mfma16(a[m], bb[n], acc[m][n]);
    }
    float bia[2];
    for (int n = 0; n < 2; ++n) bia[n] = bproj[h*32 + n*16 + l15];
    __syncthreads();   // all al reads done before ol overlays perw
    float* ol = (float*)&perw[h][0];   // [32][65] f32 = 8320 B, overlays qs+ks
    for (int n = 0; n < 2; ++n)
      for (int m = 0; m < 4; ++m)
        for (int r = 0; r < 4; ++r)
          ol[(n*16 + l15)*65 + m*16 + l16*4 + r] = acc[m][n][r] + bia[n];
    __syncthreads();   // ol visible cross-lane
    float* orow = out + ((size_t)b*256 + h*32)*4096 + hh*64;
    for (int rr = 0; rr < 32; ++rr)
      orow[(size_t)rr*4096 + lane] = ol[rr*65 + lane];
  }
}

extern "C" void kernel_launch(void* const* d_in, const int* in_sizes, int n_in,
                              void* d_out, int out_size, void* d_ws, size_t ws_size,
                              hipStream_t stream)
{
  const float* x     = (const float*)d_in[0];
  const float* wqkv  = (const float*)d_in[1];
  const float* wproj = (const float*)d_in[2];
  const float* bproj = (const float*)d_in[3];
  const float* gamma = (const float*)d_in[4];
  const float* beta  = (const float*)d_in[5];
  float* out = (float*)d_out;

  f16* ws = (f16*)d_ws;
  f16* wqkv_h  = ws;            // 196608 f16
  f16* wproj_h = ws + 196608;   // 65536 f16

  k_cvt  <<<256, 256, 0, stream>>>(wqkv, wproj, wqkv_h, wproj_h);
  k_fused<<<1024, 512, 0, stream>>>(x, gamma, beta, wqkv_h, wproj_h, bproj, out);
}